// Round 1
// baseline (428.295 us; speedup 1.0000x reference)
//
#include <hip/hip_runtime.h>
#include <hip/hip_bf16.h>
#include <math.h>

// Problem constants
#define R_   8192    // B*S rows
#define DM   1024    // d_model
#define DFF  4096    // d_ff
#define NP   64      // n_patterns
#define KN   8       // K neurons

typedef __bf16 bf16x8 __attribute__((ext_vector_type(8)));
typedef float  f32x4  __attribute__((ext_vector_type(4)));

__device__ __forceinline__ unsigned short f2bf(float f) {
  union { float f; unsigned u; } v; v.f = f;
  unsigned u = v.u;
  return (unsigned short)((u + 0x7FFFu + ((u >> 16) & 1u)) >> 16);
}

__device__ __forceinline__ float dot4(const float4 a, const float4 b) {
  return a.x * b.x + a.y * b.y + a.z * b.z + a.w * b.w;
}

__device__ __forceinline__ void fma4(float4& a, float w, const float4 s) {
  a.x += w * s.x; a.y += w * s.y; a.z += w * s.z; a.w += w * s.w;
}

// ---------------------------------------------------------------- f32 -> bf16
__global__ __launch_bounds__(256) void cvt_bf16_kernel(
    const float* __restrict__ in, unsigned short* __restrict__ out, int n8) {
  int i = blockIdx.x * 256 + threadIdx.x;
  if (i >= n8) return;
  const float4* p = (const float4*)in + (size_t)i * 2;
  float4 a = p[0], b = p[1];
  uint4 r;
  r.x = (unsigned)f2bf(a.x) | ((unsigned)f2bf(a.y) << 16);
  r.y = (unsigned)f2bf(a.z) | ((unsigned)f2bf(a.w) << 16);
  r.z = (unsigned)f2bf(b.x) | ((unsigned)f2bf(b.y) << 16);
  r.w = (unsigned)f2bf(b.z) | ((unsigned)f2bf(b.w) << 16);
  ((uint4*)out)[i] = r;
}

// ------------------------------------------------- pattern scores/topk/softmax
// One wave handles 8 positions. v[r] = sum_k w_k * sn[r,k,:] held in registers:
// lane holds d = [lane*16, lane*16+16). scores via coalesced pq reads +
// butterfly reduce; lane==pat keeps score; wave-parallel argmax top-4.
__global__ __launch_bounds__(256, 2) void pattern_kernel(
    const float* __restrict__ sn,    // [R_][8][1024]
    const float* __restrict__ tw,    // [R_][8]
    const float* __restrict__ pq,    // [64][1024]
    int*   __restrict__ out_idx,     // [R_][4]
    float* __restrict__ out_w)       // [R_][4]
{
  const int lane = threadIdx.x & 63;
  const int wave = threadIdx.x >> 6;
  const int pos0 = (blockIdx.x * 4 + wave) * 8;

  float4 vr[8][4];
#pragma unroll
  for (int p = 0; p < 8; ++p) {
    const int r = pos0 + p;
    const float* wp = tw + r * KN;
    const float* base = sn + (size_t)r * (KN * DM) + lane * 16;
    float4 a0 = {0,0,0,0}, a1 = {0,0,0,0}, a2 = {0,0,0,0}, a3 = {0,0,0,0};
#pragma unroll
    for (int k = 0; k < KN; ++k) {
      const float wk = wp[k];
      const float4* s = (const float4*)(base + k * DM);
      fma4(a0, wk, s[0]); fma4(a1, wk, s[1]);
      fma4(a2, wk, s[2]); fma4(a3, wk, s[3]);
    }
    vr[p][0] = a0; vr[p][1] = a1; vr[p][2] = a2; vr[p][3] = a3;
  }

  float sreg[8];
#pragma unroll 1
  for (int pat = 0; pat < NP; ++pat) {
    const float4* q = (const float4*)(pq + pat * DM + lane * 16);
    const float4 q0 = q[0], q1 = q[1], q2 = q[2], q3 = q[3];
    float part[8];
#pragma unroll
    for (int p = 0; p < 8; ++p)
      part[p] = dot4(q0, vr[p][0]) + dot4(q1, vr[p][1]) +
                dot4(q2, vr[p][2]) + dot4(q3, vr[p][3]);
#pragma unroll
    for (int off = 32; off >= 1; off >>= 1) {
#pragma unroll
      for (int p = 0; p < 8; ++p)
        part[p] += __shfl_xor(part[p], off, 64);
    }
    if (lane == pat) {
#pragma unroll
      for (int p = 0; p < 8; ++p) sreg[p] = part[p] * 0.03125f; // /sqrt(1024)
    }
  }

#pragma unroll
  for (int p = 0; p < 8; ++p) {
    float cur = sreg[p];
    float m0, m1, m2, m3; int i0, i1, i2, i3;
#define ARGMAX_STEP(MV, MI)                                   \
    {                                                         \
      float bv = cur; int bi = lane;                          \
      _Pragma("unroll")                                       \
      for (int off = 32; off >= 1; off >>= 1) {               \
        float ov = __shfl_xor(bv, off, 64);                   \
        int   oi = __shfl_xor(bi, off, 64);                   \
        if (ov > bv || (ov == bv && oi < bi)) { bv = ov; bi = oi; } \
      }                                                       \
      MV = bv; MI = bi;                                       \
      if (lane == bi) cur = -3.0e38f;                         \
    }
    ARGMAX_STEP(m0, i0) ARGMAX_STEP(m1, i1) ARGMAX_STEP(m2, i2) ARGMAX_STEP(m3, i3)
#undef ARGMAX_STEP
    const float e1 = __expf(m1 - m0), e2 = __expf(m2 - m0), e3 = __expf(m3 - m0);
    const float inv = 1.f / (1.f + e1 + e2 + e3);
    if (lane < 4) {
      const int r = pos0 + p;
      const int myi = (lane == 0) ? i0 : (lane == 1) ? i1 : (lane == 2) ? i2 : i3;
      const float mye = (lane == 0) ? 1.f : (lane == 1) ? e1 : (lane == 2) ? e2 : e3;
      out_idx[r * 4 + lane] = myi;
      out_w[r * 4 + lane] = mye * inv;
    }
  }
}

// ---------------------------------------------------------------- bf16 GEMM
__device__ __forceinline__ void gll16(const void* g, void* l) {
  __builtin_amdgcn_global_load_lds(
      (const __attribute__((address_space(1))) unsigned int*)g,
      (__attribute__((address_space(3))) unsigned int*)l, 16, 0, 0);
}

// C[M,N] = A[M,K] * B[N,K]^T (NT). MODE 0: gated-gelu epilogue -> bf16 H.
// MODE 1: +bias -> f32 out.
template <int K, int N, int MODE>
__global__ __launch_bounds__(256, 2) void gemm_kernel(
    const unsigned short* __restrict__ A,
    const unsigned short* __restrict__ Bm,
    const float* __restrict__ bias,
    const int*   __restrict__ pidx,
    const float* __restrict__ pwt,
    const float* __restrict__ gates,  // [64][DFF]
    void* __restrict__ Cout)
{
  __shared__ __align__(16) unsigned short As[128 * 32];
  __shared__ __align__(16) unsigned short Bs[128 * 32];
  const int tid  = threadIdx.x;
  const int lane = tid & 63;
  const int wid  = tid >> 6;
  const int wr   = wid >> 1;
  const int wc   = wid & 1;
  constexpr int NB = N / 128;
  const int brow = blockIdx.x / NB;
  const int bcol = blockIdx.x % NB;

  const unsigned short* Ab = A  + (size_t)brow * 128 * K;
  const unsigned short* Bb = Bm + (size_t)bcol * 128 * K;

  f32x4 acc[4][4];
#pragma unroll
  for (int m = 0; m < 4; ++m)
#pragma unroll
    for (int n = 0; n < 4; ++n)
      acc[m][n] = (f32x4){0.f, 0.f, 0.f, 0.f};

  const int srow = tid >> 2;            // staging row 0..63 (+64 for 2nd call)
  const int scol = (tid & 3) * 8;       // staging col (8 bf16 = 16B)
  char* ldsA = (char*)As + (tid >> 6) * 1024;  // wave-uniform base
  char* ldsB = (char*)Bs + (tid >> 6) * 1024;

  const int arow = wr * 64 + (lane & 15);
  const int bro  = wc * 64 + (lane & 15);
  const int koff = (lane >> 4) * 8;

  for (int k0 = 0; k0 < K; k0 += 32) {
    if (k0) __syncthreads();            // frag reads done before overwrite
    gll16(Ab + (size_t)srow * K + k0 + scol,        ldsA);
    gll16(Ab + (size_t)(srow + 64) * K + k0 + scol, ldsA + 4096);
    gll16(Bb + (size_t)srow * K + k0 + scol,        ldsB);
    gll16(Bb + (size_t)(srow + 64) * K + k0 + scol, ldsB + 4096);
    __syncthreads();                    // vmcnt(0) drain -> staged data visible

    bf16x8 af[4], bfr[4];
#pragma unroll
    for (int m = 0; m < 4; ++m)
      af[m] = *(const bf16x8*)(As + (arow + m * 16) * 32 + koff);
#pragma unroll
    for (int n = 0; n < 4; ++n)
      bfr[n] = *(const bf16x8*)(Bs + (bro + n * 16) * 32 + koff);
#pragma unroll
    for (int m = 0; m < 4; ++m)
#pragma unroll
      for (int n = 0; n < 4; ++n)
        acc[m][n] = __builtin_amdgcn_mfma_f32_16x16x32_bf16(
            af[m], bfr[n], acc[m][n], 0, 0, 0);
  }

  // Epilogue. C/D layout: col = lane&15, row = (lane>>4)*4 + reg.
  const int crow0 = brow * 128 + wr * 64;
  const int ccol0 = bcol * 128 + wc * 64 + (lane & 15);
  const int rsub  = (lane >> 4) * 4;

  if (MODE == 0) {
    unsigned short* H = (unsigned short*)Cout;
#pragma unroll
    for (int m = 0; m < 4; ++m) {
      const int rbase = crow0 + m * 16 + rsub;
      int   ia[4][4];
      float wa[4][4];
#pragma unroll
      for (int j = 0; j < 4; ++j) {
        const int4   iq = *(const int4*)(pidx + (size_t)(rbase + j) * 4);
        const float4 wq = *(const float4*)(pwt + (size_t)(rbase + j) * 4);
        ia[j][0] = iq.x; ia[j][1] = iq.y; ia[j][2] = iq.z; ia[j][3] = iq.w;
        wa[j][0] = wq.x; wa[j][1] = wq.y; wa[j][2] = wq.z; wa[j][3] = wq.w;
      }
#pragma unroll
      for (int n = 0; n < 4; ++n) {
        const int col = ccol0 + n * 16;
        const float ub = bias[col];
#pragma unroll
        for (int j = 0; j < 4; ++j) {
          float g = wa[j][0] * gates[(size_t)ia[j][0] * DFF + col]
                  + wa[j][1] * gates[(size_t)ia[j][1] * DFF + col]
                  + wa[j][2] * gates[(size_t)ia[j][2] * DFF + col]
                  + wa[j][3] * gates[(size_t)ia[j][3] * DFF + col];
          const float u   = acc[m][n][j] + ub;
          const float val = u * (1.f / (1.f + __expf(-g)));
          const float h   = 0.5f * val * (1.f + erff(val * 0.70710678118654752f));
          H[(size_t)(rbase + j) * N + col] = f2bf(h);
        }
      }
    }
  } else {
    float* O = (float*)Cout;
#pragma unroll
    for (int m = 0; m < 4; ++m) {
      const int rbase = crow0 + m * 16 + rsub;
#pragma unroll
      for (int n = 0; n < 4; ++n) {
        const int col = ccol0 + n * 16;
        const float db = bias[col];
#pragma unroll
        for (int j = 0; j < 4; ++j)
          O[(size_t)(rbase + j) * N + col] = acc[m][n][j] + db;
      }
    }
  }
}

// ---------------------------------------------------------------------- launch
extern "C" void kernel_launch(void* const* d_in, const int* in_sizes, int n_in,
                              void* d_out, int out_size, void* d_ws, size_t ws_size,
                              hipStream_t stream) {
  const float* x     = (const float*)d_in[0];
  // d_in[1] router_out unused, d_in[2] topk_neuron_idx unused
  const float* tw    = (const float*)d_in[3];
  const float* sn    = (const float*)d_in[4];
  const float* pq    = (const float*)d_in[5];
  const float* gates = (const float*)d_in[6];
  const float* upw   = (const float*)d_in[7];
  const float* upb   = (const float*)d_in[8];
  const float* dnw   = (const float*)d_in[9];
  const float* dnb   = (const float*)d_in[10];
  float* out = (float*)d_out;

  char* p = (char*)d_ws;
  unsigned short* xb  = (unsigned short*)p; p += (size_t)R_ * DM * 2;
  unsigned short* uwb = (unsigned short*)p; p += (size_t)DFF * DM * 2;
  unsigned short* dwb = (unsigned short*)p; p += (size_t)DM * DFF * 2;
  unsigned short* H   = (unsigned short*)p; p += (size_t)R_ * DFF * 2;
  int*   pidx = (int*)p;   p += (size_t)R_ * 4 * sizeof(int);
  float* pwt  = (float*)p; p += (size_t)R_ * 4 * sizeof(float);

  cvt_bf16_kernel<<<(R_ * DM / 8) / 256, 256, 0, stream>>>(x, xb, R_ * DM / 8);
  cvt_bf16_kernel<<<(DFF * DM / 8) / 256, 256, 0, stream>>>(upw, uwb, DFF * DM / 8);
  cvt_bf16_kernel<<<(DM * DFF / 8) / 256, 256, 0, stream>>>(dnw, dwb, DM * DFF / 8);

  pattern_kernel<<<R_ / 32, 256, 0, stream>>>(sn, tw, pq, pidx, pwt);

  gemm_kernel<DM, DFF, 0><<<(R_ / 128) * (DFF / 128), 256, 0, stream>>>(
      xb, uwb, upb, pidx, pwt, gates, (void*)H);
  gemm_kernel<DFF, DM, 1><<<(R_ / 128) * (DM / 128), 256, 0, stream>>>(
      H, dwb, dnb, nullptr, nullptr, nullptr, (void*)out);
}

// Round 2
// 408.492 us; speedup vs baseline: 1.0485x; 1.0485x over previous
//
#include <hip/hip_runtime.h>
#include <hip/hip_bf16.h>
#include <math.h>

// Problem constants
#define R_   8192    // B*S rows
#define DM   1024    // d_model
#define DFF  4096    // d_ff
#define NP   64      // n_patterns
#define KN   8       // K neurons

typedef __bf16 bf16x8 __attribute__((ext_vector_type(8)));
typedef float  f32x4  __attribute__((ext_vector_type(4)));

__device__ __forceinline__ unsigned short f2bf(float f) {
  union { float f; unsigned u; } v; v.f = f;
  unsigned u = v.u;
  return (unsigned short)((u + 0x7FFFu + ((u >> 16) & 1u)) >> 16);
}

__device__ __forceinline__ float dot4(const float4 a, const float4 b) {
  return a.x * b.x + a.y * b.y + a.z * b.z + a.w * b.w;
}

__device__ __forceinline__ void fma4(float4& a, float w, const float4 s) {
  a.x += w * s.x; a.y += w * s.y; a.z += w * s.z; a.w += w * s.w;
}

// ---------------------------------------------------------------- f32 -> bf16
__global__ __launch_bounds__(256) void cvt_bf16_kernel(
    const float* __restrict__ in, unsigned short* __restrict__ out, int n8) {
  int i = blockIdx.x * 256 + threadIdx.x;
  if (i >= n8) return;
  const float4* p = (const float4*)in + (size_t)i * 2;
  float4 a = p[0], b = p[1];
  uint4 r;
  r.x = (unsigned)f2bf(a.x) | ((unsigned)f2bf(a.y) << 16);
  r.y = (unsigned)f2bf(a.z) | ((unsigned)f2bf(a.w) << 16);
  r.z = (unsigned)f2bf(b.x) | ((unsigned)f2bf(b.y) << 16);
  r.w = (unsigned)f2bf(b.z) | ((unsigned)f2bf(b.w) << 16);
  ((uint4*)out)[i] = r;
}

// -------------------------------------------------------------- v materialize
// v[r,d] = sum_k tw[r,k] * sn[r,k,d].  One row per 256-thread block; each
// thread owns 4 contiguous d (float4). 8 independent loads/thread = good MLP.
__global__ __launch_bounds__(256) void vcomp_kernel(
    const float* __restrict__ sn,    // [R_][8][1024]
    const float* __restrict__ tw,    // [R_][8]
    float* __restrict__ v)           // [R_][1024]
{
  const int r = blockIdx.x;
  const int t = threadIdx.x;
  float w[KN];
#pragma unroll
  for (int k = 0; k < KN; ++k) w[k] = tw[(size_t)r * KN + k];
  const float* base = sn + (size_t)r * (KN * DM) + t * 4;
  float4 a = {0.f, 0.f, 0.f, 0.f};
#pragma unroll
  for (int k = 0; k < KN; ++k) fma4(a, w[k], *(const float4*)(base + k * DM));
  *(float4*)(v + (size_t)r * DM + t * 4) = a;
}

// ------------------------------------------------- pattern scores/topk/softmax
// One wave handles 4 rows; v rows are L3/L2-resident f32. Lane holds
// d = [lane*16, lane*16+16). Coalesced pq reads + butterfly reduce;
// lane==pat keeps score; wave-parallel argmax top-4 + softmax.
__global__ __launch_bounds__(256, 2) void score_kernel(
    const float* __restrict__ v,     // [R_][1024]
    const float* __restrict__ pq,    // [64][1024]
    int*   __restrict__ out_idx,     // [R_][4]
    float* __restrict__ out_w)       // [R_][4]
{
  const int lane = threadIdx.x & 63;
  const int wave = threadIdx.x >> 6;
  const int pos0 = (blockIdx.x * 4 + wave) * 4;

  float4 vr[4][4];
#pragma unroll
  for (int p = 0; p < 4; ++p) {
    const float4* s = (const float4*)(v + (size_t)(pos0 + p) * DM + lane * 16);
    vr[p][0] = s[0]; vr[p][1] = s[1]; vr[p][2] = s[2]; vr[p][3] = s[3];
  }

  float sreg[4];
#pragma unroll 1
  for (int pat = 0; pat < NP; ++pat) {
    const float4* q = (const float4*)(pq + pat * DM + lane * 16);
    const float4 q0 = q[0], q1 = q[1], q2 = q[2], q3 = q[3];
    float part[4];
#pragma unroll
    for (int p = 0; p < 4; ++p)
      part[p] = dot4(q0, vr[p][0]) + dot4(q1, vr[p][1]) +
                dot4(q2, vr[p][2]) + dot4(q3, vr[p][3]);
#pragma unroll
    for (int off = 32; off >= 1; off >>= 1) {
#pragma unroll
      for (int p = 0; p < 4; ++p)
        part[p] += __shfl_xor(part[p], off, 64);
    }
    if (lane == pat) {
#pragma unroll
      for (int p = 0; p < 4; ++p) sreg[p] = part[p] * 0.03125f; // /sqrt(1024)
    }
  }

#pragma unroll
  for (int p = 0; p < 4; ++p) {
    float cur = sreg[p];
    float m0, m1, m2, m3; int i0, i1, i2, i3;
#define ARGMAX_STEP(MV, MI)                                   \
    {                                                         \
      float bv = cur; int bi = lane;                          \
      _Pragma("unroll")                                       \
      for (int off = 32; off >= 1; off >>= 1) {               \
        float ov = __shfl_xor(bv, off, 64);                   \
        int   oi = __shfl_xor(bi, off, 64);                   \
        if (ov > bv || (ov == bv && oi < bi)) { bv = ov; bi = oi; } \
      }                                                       \
      MV = bv; MI = bi;                                       \
      if (lane == bi) cur = -3.0e38f;                         \
    }
    ARGMAX_STEP(m0, i0) ARGMAX_STEP(m1, i1) ARGMAX_STEP(m2, i2) ARGMAX_STEP(m3, i3)
#undef ARGMAX_STEP
    const float e1 = __expf(m1 - m0), e2 = __expf(m2 - m0), e3 = __expf(m3 - m0);
    const float inv = 1.f / (1.f + e1 + e2 + e3);
    if (lane < 4) {
      const int r = pos0 + p;
      const int myi = (lane == 0) ? i0 : (lane == 1) ? i1 : (lane == 2) ? i2 : i3;
      const float mye = (lane == 0) ? 1.f : (lane == 1) ? e1 : (lane == 2) ? e2 : e3;
      out_idx[r * 4 + lane] = myi;
      out_w[r * 4 + lane] = mye * inv;
    }
  }
}

// ---------------------------------------------------------------- bf16 GEMM
__device__ __forceinline__ void gll16(const void* g, void* l) {
  __builtin_amdgcn_global_load_lds(
      (const __attribute__((address_space(1))) unsigned int*)g,
      (__attribute__((address_space(3))) unsigned int*)l, 16, 0, 0);
}

// C[M,N] = A[M,K] * B[N,K]^T (NT). MODE 0: gated-gelu epilogue -> bf16 H.
// MODE 1: +bias -> f32 out.
template <int K, int N, int MODE>
__global__ __launch_bounds__(256, 2) void gemm_kernel(
    const unsigned short* __restrict__ A,
    const unsigned short* __restrict__ Bm,
    const float* __restrict__ bias,
    const int*   __restrict__ pidx,
    const float* __restrict__ pwt,
    const float* __restrict__ gates,  // [64][DFF]
    void* __restrict__ Cout)
{
  __shared__ __align__(16) unsigned short As[128 * 32];
  __shared__ __align__(16) unsigned short Bs[128 * 32];
  const int tid  = threadIdx.x;
  const int lane = tid & 63;
  const int wid  = tid >> 6;
  const int wr   = wid >> 1;
  const int wc   = wid & 1;
  constexpr int NB = N / 128;
  const int brow = blockIdx.x / NB;
  const int bcol = blockIdx.x % NB;

  const unsigned short* Ab = A  + (size_t)brow * 128 * K;
  const unsigned short* Bb = Bm + (size_t)bcol * 128 * K;

  f32x4 acc[4][4];
#pragma unroll
  for (int m = 0; m < 4; ++m)
#pragma unroll
    for (int n = 0; n < 4; ++n)
      acc[m][n] = (f32x4){0.f, 0.f, 0.f, 0.f};

  const int srow = tid >> 2;            // staging row 0..63 (+64 for 2nd call)
  const int scol = (tid & 3) * 8;       // staging col (8 bf16 = 16B)
  char* ldsA = (char*)As + (tid >> 6) * 1024;  // wave-uniform base
  char* ldsB = (char*)Bs + (tid >> 6) * 1024;

  const int arow = wr * 64 + (lane & 15);
  const int bro  = wc * 64 + (lane & 15);
  const int koff = (lane >> 4) * 8;

  for (int k0 = 0; k0 < K; k0 += 32) {
    if (k0) __syncthreads();            // frag reads done before overwrite
    gll16(Ab + (size_t)srow * K + k0 + scol,        ldsA);
    gll16(Ab + (size_t)(srow + 64) * K + k0 + scol, ldsA + 4096);
    gll16(Bb + (size_t)srow * K + k0 + scol,        ldsB);
    gll16(Bb + (size_t)(srow + 64) * K + k0 + scol, ldsB + 4096);
    __syncthreads();                    // vmcnt(0) drain -> staged data visible

    bf16x8 af[4], bfr[4];
#pragma unroll
    for (int m = 0; m < 4; ++m)
      af[m] = *(const bf16x8*)(As + (arow + m * 16) * 32 + koff);
#pragma unroll
    for (int n = 0; n < 4; ++n)
      bfr[n] = *(const bf16x8*)(Bs + (bro + n * 16) * 32 + koff);
#pragma unroll
    for (int m = 0; m < 4; ++m)
#pragma unroll
      for (int n = 0; n < 4; ++n)
        acc[m][n] = __builtin_amdgcn_mfma_f32_16x16x32_bf16(
            af[m], bfr[n], acc[m][n], 0, 0, 0);
  }

  // Epilogue. C/D layout: col = lane&15, row = (lane>>4)*4 + reg.
  const int crow0 = brow * 128 + wr * 64;
  const int ccol0 = bcol * 128 + wc * 64 + (lane & 15);
  const int rsub  = (lane >> 4) * 4;

  if (MODE == 0) {
    unsigned short* H = (unsigned short*)Cout;
#pragma unroll
    for (int m = 0; m < 4; ++m) {
      const int rbase = crow0 + m * 16 + rsub;
      int   ia[4][4];
      float wa[4][4];
#pragma unroll
      for (int j = 0; j < 4; ++j) {
        const int4   iq = *(const int4*)(pidx + (size_t)(rbase + j) * 4);
        const float4 wq = *(const float4*)(pwt + (size_t)(rbase + j) * 4);
        ia[j][0] = iq.x; ia[j][1] = iq.y; ia[j][2] = iq.z; ia[j][3] = iq.w;
        wa[j][0] = wq.x; wa[j][1] = wq.y; wa[j][2] = wq.z; wa[j][3] = wq.w;
      }
#pragma unroll
      for (int n = 0; n < 4; ++n) {
        const int col = ccol0 + n * 16;
        const float ub = bias[col];
#pragma unroll
        for (int j = 0; j < 4; ++j) {
          float g = wa[j][0] * gates[(size_t)ia[j][0] * DFF + col]
                  + wa[j][1] * gates[(size_t)ia[j][1] * DFF + col]
                  + wa[j][2] * gates[(size_t)ia[j][2] * DFF + col]
                  + wa[j][3] * gates[(size_t)ia[j][3] * DFF + col];
          const float u   = acc[m][n][j] + ub;
          const float val = u * (1.f / (1.f + __expf(-g)));
          const float h   = 0.5f * val * (1.f + erff(val * 0.70710678118654752f));
          H[(size_t)(rbase + j) * N + col] = f2bf(h);
        }
      }
    }
  } else {
    float* O = (float*)Cout;
#pragma unroll
    for (int m = 0; m < 4; ++m) {
      const int rbase = crow0 + m * 16 + rsub;
#pragma unroll
      for (int n = 0; n < 4; ++n) {
        const int col = ccol0 + n * 16;
        const float db = bias[col];
#pragma unroll
        for (int j = 0; j < 4; ++j)
          O[(size_t)(rbase + j) * N + col] = acc[m][n][j] + db;
      }
    }
  }
}

// ---------------------------------------------------------------------- launch
extern "C" void kernel_launch(void* const* d_in, const int* in_sizes, int n_in,
                              void* d_out, int out_size, void* d_ws, size_t ws_size,
                              hipStream_t stream) {
  const float* x     = (const float*)d_in[0];
  // d_in[1] router_out unused, d_in[2] topk_neuron_idx unused
  const float* tw    = (const float*)d_in[3];
  const float* sn    = (const float*)d_in[4];
  const float* pq    = (const float*)d_in[5];
  const float* gates = (const float*)d_in[6];
  const float* upw   = (const float*)d_in[7];
  const float* upb   = (const float*)d_in[8];
  const float* dnw   = (const float*)d_in[9];
  const float* dnb   = (const float*)d_in[10];
  float* out = (float*)d_out;

  char* p = (char*)d_ws;
  unsigned short* xb  = (unsigned short*)p; p += (size_t)R_ * DM * 2;
  unsigned short* uwb = (unsigned short*)p; p += (size_t)DFF * DM * 2;
  unsigned short* dwb = (unsigned short*)p; p += (size_t)DM * DFF * 2;
  unsigned short* H   = (unsigned short*)p; p += (size_t)R_ * DFF * 2;
  int*   pidx = (int*)p;   p += (size_t)R_ * 4 * sizeof(int);
  float* pwt  = (float*)p; p += (size_t)R_ * 4 * sizeof(float);
  float* vbuf = (float*)p; p += (size_t)R_ * DM * sizeof(float);

  cvt_bf16_kernel<<<(R_ * DM / 8) / 256, 256, 0, stream>>>(x, xb, R_ * DM / 8);
  cvt_bf16_kernel<<<(DFF * DM / 8) / 256, 256, 0, stream>>>(upw, uwb, DFF * DM / 8);
  cvt_bf16_kernel<<<(DM * DFF / 8) / 256, 256, 0, stream>>>(dnw, dwb, DM * DFF / 8);

  vcomp_kernel<<<R_, 256, 0, stream>>>(sn, tw, vbuf);
  score_kernel<<<R_ / 16, 256, 0, stream>>>(vbuf, pq, pidx, pwt);

  gemm_kernel<DM, DFF, 0><<<(R_ / 128) * (DFF / 128), 256, 0, stream>>>(
      xb, uwb, upb, pidx, pwt, gates, (void*)H);
  gemm_kernel<DFF, DM, 1><<<(R_ / 128) * (DM / 128), 256, 0, stream>>>(
      H, dwb, dnb, nullptr, nullptr, nullptr, (void*)out);
}

// Round 3
// 377.834 us; speedup vs baseline: 1.1336x; 1.0811x over previous
//
#include <hip/hip_runtime.h>
#include <hip/hip_bf16.h>
#include <math.h>

// Problem constants
#define R_   8192    // B*S rows
#define DM   1024    // d_model
#define DFF  4096    // d_ff
#define NP   64      // n_patterns
#define KN   8       // K neurons

typedef __bf16 bf16x8 __attribute__((ext_vector_type(8)));
typedef float  f32x4  __attribute__((ext_vector_type(4)));

__device__ __forceinline__ unsigned short f2bf(float f) {
  union { float f; unsigned u; } v; v.f = f;
  unsigned u = v.u;
  return (unsigned short)((u + 0x7FFFu + ((u >> 16) & 1u)) >> 16);
}

__device__ __forceinline__ float dot4(const float4 a, const float4 b) {
  return a.x * b.x + a.y * b.y + a.z * b.z + a.w * b.w;
}

__device__ __forceinline__ void fma4(float4& a, float w, const float4 s) {
  a.x += w * s.x; a.y += w * s.y; a.z += w * s.z; a.w += w * s.w;
}

// ---------------------------------------------------------------- f32 -> bf16
__global__ __launch_bounds__(256) void cvt_bf16_kernel(
    const float* __restrict__ in, unsigned short* __restrict__ out, int n8) {
  int i = blockIdx.x * 256 + threadIdx.x;
  if (i >= n8) return;
  const float4* p = (const float4*)in + (size_t)i * 2;
  float4 a = p[0], b = p[1];
  uint4 r;
  r.x = (unsigned)f2bf(a.x) | ((unsigned)f2bf(a.y) << 16);
  r.y = (unsigned)f2bf(a.z) | ((unsigned)f2bf(a.w) << 16);
  r.z = (unsigned)f2bf(b.x) | ((unsigned)f2bf(b.y) << 16);
  r.w = (unsigned)f2bf(b.z) | ((unsigned)f2bf(b.w) << 16);
  ((uint4*)out)[i] = r;
}

// -------------------------------------------------------------- v materialize
__global__ __launch_bounds__(256) void vcomp_kernel(
    const float* __restrict__ sn,    // [R_][8][1024]
    const float* __restrict__ tw,    // [R_][8]
    float* __restrict__ v)           // [R_][1024]
{
  const int r = blockIdx.x;
  const int t = threadIdx.x;
  float w[KN];
#pragma unroll
  for (int k = 0; k < KN; ++k) w[k] = tw[(size_t)r * KN + k];
  const float* base = sn + (size_t)r * (KN * DM) + t * 4;
  float4 a = {0.f, 0.f, 0.f, 0.f};
#pragma unroll
  for (int k = 0; k < KN; ++k) fma4(a, w[k], *(const float4*)(base + k * DM));
  *(float4*)(v + (size_t)r * DM + t * 4) = a;
}

// ------------------------------------------------- pattern scores/topk/softmax
__global__ __launch_bounds__(256, 2) void score_kernel(
    const float* __restrict__ v,     // [R_][1024]
    const float* __restrict__ pq,    // [64][1024]
    int*   __restrict__ out_idx,     // [R_][4]
    float* __restrict__ out_w)       // [R_][4]
{
  const int lane = threadIdx.x & 63;
  const int wave = threadIdx.x >> 6;
  const int pos0 = (blockIdx.x * 4 + wave) * 4;

  float4 vr[4][4];
#pragma unroll
  for (int p = 0; p < 4; ++p) {
    const float4* s = (const float4*)(v + (size_t)(pos0 + p) * DM + lane * 16);
    vr[p][0] = s[0]; vr[p][1] = s[1]; vr[p][2] = s[2]; vr[p][3] = s[3];
  }

  float sreg[4];
#pragma unroll 1
  for (int pat = 0; pat < NP; ++pat) {
    const float4* q = (const float4*)(pq + pat * DM + lane * 16);
    const float4 q0 = q[0], q1 = q[1], q2 = q[2], q3 = q[3];
    float part[4];
#pragma unroll
    for (int p = 0; p < 4; ++p)
      part[p] = dot4(q0, vr[p][0]) + dot4(q1, vr[p][1]) +
                dot4(q2, vr[p][2]) + dot4(q3, vr[p][3]);
#pragma unroll
    for (int off = 32; off >= 1; off >>= 1) {
#pragma unroll
      for (int p = 0; p < 4; ++p)
        part[p] += __shfl_xor(part[p], off, 64);
    }
    if (lane == pat) {
#pragma unroll
      for (int p = 0; p < 4; ++p) sreg[p] = part[p] * 0.03125f; // /sqrt(1024)
    }
  }

#pragma unroll
  for (int p = 0; p < 4; ++p) {
    float cur = sreg[p];
    float m0, m1, m2, m3; int i0, i1, i2, i3;
#define ARGMAX_STEP(MV, MI)                                   \
    {                                                         \
      float bv = cur; int bi = lane;                          \
      _Pragma("unroll")                                       \
      for (int off = 32; off >= 1; off >>= 1) {               \
        float ov = __shfl_xor(bv, off, 64);                   \
        int   oi = __shfl_xor(bi, off, 64);                   \
        if (ov > bv || (ov == bv && oi < bi)) { bv = ov; bi = oi; } \
      }                                                       \
      MV = bv; MI = bi;                                       \
      if (lane == bi) cur = -3.0e38f;                         \
    }
    ARGMAX_STEP(m0, i0) ARGMAX_STEP(m1, i1) ARGMAX_STEP(m2, i2) ARGMAX_STEP(m3, i3)
#undef ARGMAX_STEP
    const float e1 = __expf(m1 - m0), e2 = __expf(m2 - m0), e3 = __expf(m3 - m0);
    const float inv = 1.f / (1.f + e1 + e2 + e3);
    if (lane < 4) {
      const int r = pos0 + p;
      const int myi = (lane == 0) ? i0 : (lane == 1) ? i1 : (lane == 2) ? i2 : i3;
      const float mye = (lane == 0) ? 1.f : (lane == 1) ? e1 : (lane == 2) ? e2 : e3;
      out_idx[r * 4 + lane] = myi;
      out_w[r * 4 + lane] = mye * inv;
    }
  }
}

// ---------------------------------------------------------------- bf16 GEMM
__device__ __forceinline__ void gll16(const void* g, void* l) {
  __builtin_amdgcn_global_load_lds(
      (const __attribute__((address_space(1))) unsigned int*)g,
      (__attribute__((address_space(3))) unsigned int*)l, 16, 0, 0);
}

// Deep-pipelined NT GEMM: C[M,N] = A[M,K]*B[N,K]^T.
// 512 thr / 8 waves; BK=32; LDS ring of RING tiles (dynamic LDS);
// reg-frag double bank (JIT read of tile s+1 while MFMA'ing tile s);
// counted vmcnt keeps (RING-3) tiles of global_load_lds in flight across
// barriers (T3+T4); setprio around MFMA cluster (T5); XCD swizzle (T1).
// Hazard ledger (verified by hand):
//   iter s: read tile s+1 (confirmed by iter s-1's vmcnt + barrier),
//           stage tile s+RING-1 into buf[(s-1)%RING] (its reads ended iter s-2,
//           >=2 barriers back), vmcnt(KEEP) confirms tile s+2 for iter s+1.
template <int K, int N, int BM, int BN, int WM, int WN, int RING, int MODE>
__global__ __launch_bounds__(512, 2) void gemm_kernel(
    const unsigned short* __restrict__ A,
    const unsigned short* __restrict__ Bm,
    const float* __restrict__ bias,
    const int*   __restrict__ pidx,
    const float* __restrict__ pwt,
    const float* __restrict__ gates,  // [64][DFF]
    void* __restrict__ Cout)
{
  extern __shared__ char smem[];
  constexpr int NT     = K / 32;
  constexpr int MF     = WM / 16;
  constexpr int NF     = WN / 16;
  constexpr int NWC    = BN / WN;       // waves along N
  constexpr int LA     = BM / 128;      // gll16 calls per thread for A
  constexpr int LB     = BN / 128;
  constexpr int KEEP   = (RING - 3) * (LA + LB);
  constexpr int TILE_A = BM * 64;       // bytes (BM rows x 32 bf16)
  constexpr int TILE   = TILE_A + BN * 64;
  constexpr int NBN    = N / BN;

  const int tid  = threadIdx.x;
  const int lane = tid & 63;
  const int wid  = tid >> 6;
  const int wr   = wid / NWC;
  const int wc   = wid % NWC;

  // XCD-aware bijective swizzle (grid % 8 == 0 for both instantiations)
  const int grid = gridDim.x;
  const int cpx  = grid >> 3;
  const int swz  = (blockIdx.x & 7) * cpx + (blockIdx.x >> 3);
  const int brow = swz / NBN;
  const int bcol = swz % NBN;

  const unsigned short* Ab = A  + (size_t)brow * BM * K;
  const unsigned short* Bb = Bm + (size_t)bcol * BN * K;

  // staging source element offsets (linear LDS <-> linear global)
  int aoffE[LA], boffE[LB];
#pragma unroll
  for (int i = 0; i < LA; ++i)
    aoffE[i] = (i * 128 + wid * 16 + (lane >> 2)) * K + (lane & 3) * 8;
#pragma unroll
  for (int i = 0; i < LB; ++i)
    boffE[i] = (i * 128 + wid * 16 + (lane >> 2)) * K + (lane & 3) * 8;

  // fragment read byte offsets (within tile region)
  const int ard = (wr * WM + (lane & 15)) * 64 + (lane >> 4) * 16;
  const int brd = (wc * WN + (lane & 15)) * 64 + (lane >> 4) * 16;

  f32x4 acc[MF][NF];
#pragma unroll
  for (int m = 0; m < MF; ++m)
#pragma unroll
    for (int n = 0; n < NF; ++n)
      acc[m][n] = (f32x4){0.f, 0.f, 0.f, 0.f};

  bf16x8 fa0[MF], fb0[NF], fa1[MF], fb1[NF];

  // ---- prologue: stage tiles 0..RING-2, confirm tiles 0..1, read tile 0
  for (int t = 0; t < RING - 1; ++t) {
    const int kE = t * 32;
    char* sba = smem + t * TILE;
#pragma unroll
    for (int i = 0; i < LA; ++i)
      gll16(Ab + kE + aoffE[i], sba + i * 8192 + wid * 1024);
#pragma unroll
    for (int i = 0; i < LB; ++i)
      gll16(Bb + kE + boffE[i], sba + TILE_A + i * 8192 + wid * 1024);
  }
  asm volatile("s_waitcnt vmcnt(%0)" ::"i"(KEEP) : "memory");
  __builtin_amdgcn_s_barrier();
  {
    const char* abase = smem + ard;
    const char* bbase = smem + TILE_A + brd;
#pragma unroll
    for (int m = 0; m < MF; ++m) fa0[m] = *(const bf16x8*)(abase + m * 1024);
#pragma unroll
    for (int n = 0; n < NF; ++n) fb0[n] = *(const bf16x8*)(bbase + n * 1024);
  }
  int rb = 1, sb = RING - 1;

#define GITER(S, FAC, FBC, FAN, FBN)                                          \
  {                                                                           \
    if ((S) + 1 < NT) {                                                       \
      const char* abase = smem + rb * TILE + ard;                             \
      const char* bbase = smem + rb * TILE + TILE_A + brd;                    \
      _Pragma("unroll") for (int m = 0; m < MF; ++m)                          \
        FAN[m] = *(const bf16x8*)(abase + m * 1024);                          \
      _Pragma("unroll") for (int n = 0; n < NF; ++n)                          \
        FBN[n] = *(const bf16x8*)(bbase + n * 1024);                          \
    }                                                                         \
    if ((S) + RING - 1 < NT) {                                                \
      const int kE = ((S) + RING - 1) * 32;                                   \
      char* sba = smem + sb * TILE;                                           \
      _Pragma("unroll") for (int i = 0; i < LA; ++i)                          \
        gll16(Ab + kE + aoffE[i], sba + i * 8192 + wid * 1024);               \
      _Pragma("unroll") for (int i = 0; i < LB; ++i)                          \
        gll16(Bb + kE + boffE[i], sba + TILE_A + i * 8192 + wid * 1024);      \
      asm volatile("s_waitcnt vmcnt(%0)" ::"i"(KEEP) : "memory");             \
    } else {                                                                  \
      asm volatile("s_waitcnt vmcnt(0)" ::: "memory");                        \
    }                                                                         \
    __builtin_amdgcn_s_barrier();                                             \
    __builtin_amdgcn_s_setprio(1);                                            \
    _Pragma("unroll") for (int m = 0; m < MF; ++m)                            \
      _Pragma("unroll") for (int n = 0; n < NF; ++n)                          \
        acc[m][n] = __builtin_amdgcn_mfma_f32_16x16x32_bf16(                  \
            FAC[m], FBC[n], acc[m][n], 0, 0, 0);                              \
    __builtin_amdgcn_s_setprio(0);                                            \
    __builtin_amdgcn_s_barrier();                                             \
    rb = rb + 1 == RING ? 0 : rb + 1;                                         \
    sb = sb + 1 == RING ? 0 : sb + 1;                                         \
  }

  for (int s = 0; s < NT; s += 2) {
    GITER(s, fa0, fb0, fa1, fb1);
    GITER(s + 1, fa1, fb1, fa0, fb0);
  }
#undef GITER

  // ---- epilogue. C/D layout: col = lane&15, row = (lane>>4)*4 + j.
  const int crow0 = brow * BM + wr * WM;
  const int ccol0 = bcol * BN + wc * WN + (lane & 15);
  const int rsub  = (lane >> 4) * 4;

  if (MODE == 0) {
    unsigned short* H = (unsigned short*)Cout;
#pragma unroll
    for (int m = 0; m < MF; ++m) {
      const int rbase = crow0 + m * 16 + rsub;
      int   ia[4][4];
      float wa[4][4];
#pragma unroll
      for (int j = 0; j < 4; ++j) {
        const int4   iq = *(const int4*)(pidx + (size_t)(rbase + j) * 4);
        const float4 wq = *(const float4*)(pwt + (size_t)(rbase + j) * 4);
        ia[j][0] = iq.x; ia[j][1] = iq.y; ia[j][2] = iq.z; ia[j][3] = iq.w;
        wa[j][0] = wq.x; wa[j][1] = wq.y; wa[j][2] = wq.z; wa[j][3] = wq.w;
      }
#pragma unroll
      for (int n = 0; n < NF; ++n) {
        const int col = ccol0 + n * 16;
        const float ub = bias[col];
#pragma unroll
        for (int j = 0; j < 4; ++j) {
          float g = wa[j][0] * gates[(size_t)ia[j][0] * DFF + col]
                  + wa[j][1] * gates[(size_t)ia[j][1] * DFF + col]
                  + wa[j][2] * gates[(size_t)ia[j][2] * DFF + col]
                  + wa[j][3] * gates[(size_t)ia[j][3] * DFF + col];
          const float u   = acc[m][n][j] + ub;
          const float val = u * (1.f / (1.f + __expf(-g)));
          const float h   = 0.5f * val * (1.f + erff(val * 0.70710678118654752f));
          H[(size_t)(rbase + j) * N + col] = f2bf(h);
        }
      }
    }
  } else {
    float* O = (float*)Cout;
#pragma unroll
    for (int m = 0; m < MF; ++m) {
      const int rbase = crow0 + m * 16 + rsub;
#pragma unroll
      for (int n = 0; n < NF; ++n) {
        const int col = ccol0 + n * 16;
        const float db = bias[col];
#pragma unroll
        for (int j = 0; j < 4; ++j)
          O[(size_t)(rbase + j) * N + col] = acc[m][n][j] + db;
      }
    }
  }
}

// ---------------------------------------------------------------------- launch
extern "C" void kernel_launch(void* const* d_in, const int* in_sizes, int n_in,
                              void* d_out, int out_size, void* d_ws, size_t ws_size,
                              hipStream_t stream) {
  const float* x     = (const float*)d_in[0];
  const float* tw    = (const float*)d_in[3];
  const float* sn    = (const float*)d_in[4];
  const float* pq    = (const float*)d_in[5];
  const float* gates = (const float*)d_in[6];
  const float* upw   = (const float*)d_in[7];
  const float* upb   = (const float*)d_in[8];
  const float* dnw   = (const float*)d_in[9];
  const float* dnb   = (const float*)d_in[10];
  float* out = (float*)d_out;

  char* p = (char*)d_ws;
  unsigned short* xb  = (unsigned short*)p; p += (size_t)R_ * DM * 2;
  unsigned short* uwb = (unsigned short*)p; p += (size_t)DFF * DM * 2;
  unsigned short* dwb = (unsigned short*)p; p += (size_t)DM * DFF * 2;
  unsigned short* H   = (unsigned short*)p; p += (size_t)R_ * DFF * 2;
  int*   pidx = (int*)p;   p += (size_t)R_ * 4 * sizeof(int);
  float* pwt  = (float*)p; p += (size_t)R_ * 4 * sizeof(float);
  float* vbuf = (float*)p; p += (size_t)R_ * DM * sizeof(float);

  cvt_bf16_kernel<<<(R_ * DM / 8) / 256, 256, 0, stream>>>(x, xb, R_ * DM / 8);
  cvt_bf16_kernel<<<(DFF * DM / 8) / 256, 256, 0, stream>>>(upw, uwb, DFF * DM / 8);
  cvt_bf16_kernel<<<(DM * DFF / 8) / 256, 256, 0, stream>>>(dnw, dwb, DM * DFF / 8);

  vcomp_kernel<<<R_, 256, 0, stream>>>(sn, tw, vbuf);
  score_kernel<<<R_ / 16, 256, 0, stream>>>(vbuf, pq, pidx, pwt);

  // GEMM1: M=8192 N=4096 K=1024, tile 256x256, waves 2x4, RING=4 (128 KB LDS)
  auto* k1 = gemm_kernel<DM, DFF, 256, 256, 128, 64, 4, 0>;
  // GEMM2: M=8192 N=1024 K=4096, tile 256x128, waves 4x2, RING=6 (144 KB LDS)
  auto* k2 = gemm_kernel<DFF, DM, 256, 128, 64, 64, 6, 1>;
  hipFuncSetAttribute((const void*)k1, hipFuncAttributeMaxDynamicSharedMemorySize,
                      4 * (256 + 256) * 64);
  hipFuncSetAttribute((const void*)k2, hipFuncAttributeMaxDynamicSharedMemorySize,
                      6 * (256 + 128) * 64);

  k1<<<(R_ / 256) * (DFF / 256), 512, 4 * (256 + 256) * 64, stream>>>(
      xb, uwb, upb, pidx, pwt, gates, (void*)H);
  k2<<<(R_ / 256) * (DM / 128), 512, 6 * (256 + 128) * 64, stream>>>(
      H, dwb, dnb, nullptr, nullptr, nullptr, (void*)out);
}

// Round 4
// 368.041 us; speedup vs baseline: 1.1637x; 1.0266x over previous
//
#include <hip/hip_runtime.h>
#include <hip/hip_bf16.h>
#include <math.h>

// Problem constants
#define R_   8192    // B*S rows
#define DM   1024    // d_model
#define DFF  4096    // d_ff
#define NP   64      // n_patterns
#define KN   8       // K neurons

typedef __bf16 bf16x8 __attribute__((ext_vector_type(8)));
typedef float  f32x4  __attribute__((ext_vector_type(4)));

__device__ __forceinline__ unsigned short f2bf(float f) {
  union { float f; unsigned u; } v; v.f = f;
  unsigned u = v.u;
  return (unsigned short)((u + 0x7FFFu + ((u >> 16) & 1u)) >> 16);
}

__device__ __forceinline__ float dot4(const float4 a, const float4 b) {
  return a.x * b.x + a.y * b.y + a.z * b.z + a.w * b.w;
}

__device__ __forceinline__ void fma4(float4& a, float w, const float4 s) {
  a.x += w * s.x; a.y += w * s.y; a.z += w * s.z; a.w += w * s.w;
}

// ---------------------------------------------------------------- f32 -> bf16
__global__ __launch_bounds__(256) void cvt_bf16_kernel(
    const float* __restrict__ in, unsigned short* __restrict__ out, int n8) {
  int i = blockIdx.x * 256 + threadIdx.x;
  if (i >= n8) return;
  const float4* p = (const float4*)in + (size_t)i * 2;
  float4 a = p[0], b = p[1];
  uint4 r;
  r.x = (unsigned)f2bf(a.x) | ((unsigned)f2bf(a.y) << 16);
  r.y = (unsigned)f2bf(a.z) | ((unsigned)f2bf(a.w) << 16);
  r.z = (unsigned)f2bf(b.x) | ((unsigned)f2bf(b.y) << 16);
  r.w = (unsigned)f2bf(b.z) | ((unsigned)f2bf(b.w) << 16);
  ((uint4*)out)[i] = r;
}

// -------------------------------------------------------------- v materialize
__global__ __launch_bounds__(256) void vcomp_kernel(
    const float* __restrict__ sn,    // [R_][8][1024]
    const float* __restrict__ tw,    // [R_][8]
    float* __restrict__ v)           // [R_][1024]
{
  const int r = blockIdx.x;
  const int t = threadIdx.x;
  float w[KN];
#pragma unroll
  for (int k = 0; k < KN; ++k) w[k] = tw[(size_t)r * KN + k];
  const float* base = sn + (size_t)r * (KN * DM) + t * 4;
  float4 a = {0.f, 0.f, 0.f, 0.f};
#pragma unroll
  for (int k = 0; k < KN; ++k) fma4(a, w[k], *(const float4*)(base + k * DM));
  *(float4*)(v + (size_t)r * DM + t * 4) = a;
}

// ------------------------------------------------- pattern scores/topk/softmax
__global__ __launch_bounds__(256, 2) void score_kernel(
    const float* __restrict__ v,     // [R_][1024]
    const float* __restrict__ pq,    // [64][1024]
    int*   __restrict__ out_idx,     // [R_][4]
    float* __restrict__ out_w)       // [R_][4]
{
  const int lane = threadIdx.x & 63;
  const int wave = threadIdx.x >> 6;
  const int pos0 = (blockIdx.x * 4 + wave) * 4;

  float4 vr[4][4];
#pragma unroll
  for (int p = 0; p < 4; ++p) {
    const float4* s = (const float4*)(v + (size_t)(pos0 + p) * DM + lane * 16);
    vr[p][0] = s[0]; vr[p][1] = s[1]; vr[p][2] = s[2]; vr[p][3] = s[3];
  }

  float sreg[4];
#pragma unroll 1
  for (int pat = 0; pat < NP; ++pat) {
    const float4* q = (const float4*)(pq + pat * DM + lane * 16);
    const float4 q0 = q[0], q1 = q[1], q2 = q[2], q3 = q[3];
    float part[4];
#pragma unroll
    for (int p = 0; p < 4; ++p)
      part[p] = dot4(q0, vr[p][0]) + dot4(q1, vr[p][1]) +
                dot4(q2, vr[p][2]) + dot4(q3, vr[p][3]);
#pragma unroll
    for (int off = 32; off >= 1; off >>= 1) {
#pragma unroll
      for (int p = 0; p < 4; ++p)
        part[p] += __shfl_xor(part[p], off, 64);
    }
    if (lane == pat) {
#pragma unroll
      for (int p = 0; p < 4; ++p) sreg[p] = part[p] * 0.03125f; // /sqrt(1024)
    }
  }

#pragma unroll
  for (int p = 0; p < 4; ++p) {
    float cur = sreg[p];
    float m0, m1, m2, m3; int i0, i1, i2, i3;
#define ARGMAX_STEP(MV, MI)                                   \
    {                                                         \
      float bv = cur; int bi = lane;                          \
      _Pragma("unroll")                                       \
      for (int off = 32; off >= 1; off >>= 1) {               \
        float ov = __shfl_xor(bv, off, 64);                   \
        int   oi = __shfl_xor(bi, off, 64);                   \
        if (ov > bv || (ov == bv && oi < bi)) { bv = ov; bi = oi; } \
      }                                                       \
      MV = bv; MI = bi;                                       \
      if (lane == bi) cur = -3.0e38f;                         \
    }
    ARGMAX_STEP(m0, i0) ARGMAX_STEP(m1, i1) ARGMAX_STEP(m2, i2) ARGMAX_STEP(m3, i3)
#undef ARGMAX_STEP
    const float e1 = __expf(m1 - m0), e2 = __expf(m2 - m0), e3 = __expf(m3 - m0);
    const float inv = 1.f / (1.f + e1 + e2 + e3);
    if (lane < 4) {
      const int r = pos0 + p;
      const int myi = (lane == 0) ? i0 : (lane == 1) ? i1 : (lane == 2) ? i2 : i3;
      const float mye = (lane == 0) ? 1.f : (lane == 1) ? e1 : (lane == 2) ? e2 : e3;
      out_idx[r * 4 + lane] = myi;
      out_w[r * 4 + lane] = mye * inv;
    }
  }
}

// ---------------------------------------------------------------- bf16 GEMM
__device__ __forceinline__ void gll16(const void* g, void* l) {
  __builtin_amdgcn_global_load_lds(
      (const __attribute__((address_space(1))) unsigned int*)g,
      (__attribute__((address_space(3))) unsigned int*)l, 16, 0, 0);
}

// Deep-pipelined NT GEMM with conflict-free XOR-swizzled LDS.
// LDS layout: element (row, slot k) [16B slots, 4/row] stored at slot
// k ^ ((row>>1)&3).  Writer (global_load_lds is linear): lane loads global
// slot (lane&3)^((lane>>3)&3) so linear LDS ends up swizzled.  Reader:
// slot = (lane>>4) ^ ((lane>>1)&3).  Per-quarter-wave bank spread = 2-way
// (free).  RING=4 x BK=32 LDS ring, compile-time indices (4x unroll);
// counted vmcnt keeps 2 tiles in flight across barriers; ds_reads of tile
// s+1 overlap the MFMA cluster of tile s (separate pipes).
// Ledger: stage(s+3,slot (s+3)%4) vs reads of tile s-1 (same slot, iter s-2
// region-2): >=2 barriers apart. Reads of tile s+1 (iter s region-2) are
// confirmed by iter s's vmcnt (KEEPM leaves tiles s+2,s+3 in flight).
template <int K, int N, int BM, int BN, int WM, int WN, int MODE>
__global__ __launch_bounds__(512, 2) void gemm_kernel(
    const unsigned short* __restrict__ A,
    const unsigned short* __restrict__ Bm,
    const float* __restrict__ bias,
    const int*   __restrict__ pidx,
    const float* __restrict__ pwt,
    const float* __restrict__ gates,  // [64][DFF]
    void* __restrict__ Cout)
{
  extern __shared__ char smem[];
  constexpr int NT     = K / 32;       // K-tiles (multiple of 4)
  constexpr int MF     = WM / 16;
  constexpr int NF     = WN / 16;
  constexpr int NWC    = BN / WN;
  constexpr int LA     = BM / 128;
  constexpr int LB     = BN / 128;
  constexpr int KEEPM  = 2 * (LA + LB);   // confirm tile s+1, keep 2 in flight
  constexpr int KEEP1  = (LA + LB);
  constexpr int TILE_A = BM * 64;
  constexpr int TILE   = TILE_A + BN * 64;
  constexpr int NBN    = N / BN;

  const int tid  = threadIdx.x;
  const int lane = tid & 63;
  const int wid  = tid >> 6;
  const int wr   = wid / NWC;
  const int wc   = wid % NWC;

  const int grid = gridDim.x;
  const int cpx  = grid >> 3;
  const int swzb = (blockIdx.x & 7) * cpx + (blockIdx.x >> 3);
  const int brow = swzb / NBN;
  const int bcol = swzb % NBN;

  const unsigned short* Ab = A  + (size_t)brow * BM * K;
  const unsigned short* Bb = Bm + (size_t)bcol * BN * K;

  // staging global source offsets, pre-swizzled (see header comment)
  const int sswz = ((lane & 3) ^ ((lane >> 3) & 3)) * 8;
  int aoffE[LA], boffE[LB];
#pragma unroll
  for (int i = 0; i < LA; ++i)
    aoffE[i] = (i * 128 + wid * 16 + (lane >> 2)) * K + sswz;
#pragma unroll
  for (int i = 0; i < LB; ++i)
    boffE[i] = (i * 128 + wid * 16 + (lane >> 2)) * K + sswz;

  // fragment read byte offsets (swizzled slot)
  const int rswz = ((lane >> 4) ^ ((lane >> 1) & 3)) * 16;
  const int ard  = (wr * WM + (lane & 15)) * 64 + rswz;
  const int brd  = (wc * WN + (lane & 15)) * 64 + rswz;

  f32x4 acc[MF][NF];
#pragma unroll
  for (int m = 0; m < MF; ++m)
#pragma unroll
    for (int n = 0; n < NF; ++n)
      acc[m][n] = (f32x4){0.f, 0.f, 0.f, 0.f};

  bf16x8 fa0[MF], fb0[NF], fa1[MF], fb1[NF];

#define STAGE(S, SB)                                                        \
  {                                                                         \
    const int kE = (S) * 32;                                                \
    char* sba = smem + (SB) * TILE;                                         \
    _Pragma("unroll") for (int i = 0; i < LA; ++i)                          \
      gll16(Ab + kE + aoffE[i], sba + i * 8192 + wid * 1024);               \
    _Pragma("unroll") for (int i = 0; i < LB; ++i)                          \
      gll16(Bb + kE + boffE[i], sba + TILE_A + i * 8192 + wid * 1024);      \
  }

  // ---- prologue: stage tiles 0..2; confirm tile 0; read its fragments
  STAGE(0, 0) STAGE(1, 1) STAGE(2, 2)
  asm volatile("s_waitcnt vmcnt(%0)" ::"i"(KEEPM) : "memory");
  __builtin_amdgcn_s_barrier();
  {
    const char* ab = smem + ard;
    const char* bb = smem + TILE_A + brd;
#pragma unroll
    for (int m = 0; m < MF; ++m) fa0[m] = *(const bf16x8*)(ab + m * 1024);
#pragma unroll
    for (int n = 0; n < NF; ++n) fb0[n] = *(const bf16x8*)(bb + n * 1024);
  }

#define GITER(S, RB, SB, DOSTAGE, KEEPV, DOREAD, FAC, FBC, FAN, FBN)        \
  {                                                                         \
    if (DOSTAGE) STAGE((S) + 3, SB)                                         \
    asm volatile("s_waitcnt vmcnt(%0)" ::"i"(KEEPV) : "memory");            \
    __builtin_amdgcn_s_barrier();                                           \
    if (DOREAD) {                                                           \
      const char* ab = smem + (RB) * TILE + ard;                            \
      const char* bb = smem + (RB) * TILE + TILE_A + brd;                   \
      _Pragma("unroll") for (int m = 0; m < MF; ++m)                        \
        FAN[m] = *(const bf16x8*)(ab + m * 1024);                           \
      _Pragma("unroll") for (int n = 0; n < NF; ++n)                        \
        FBN[n] = *(const bf16x8*)(bb + n * 1024);                           \
    }                                                                       \
    __builtin_amdgcn_s_setprio(1);                                          \
    _Pragma("unroll") for (int m = 0; m < MF; ++m)                          \
      _Pragma("unroll") for (int n = 0; n < NF; ++n)                        \
        acc[m][n] = __builtin_amdgcn_mfma_f32_16x16x32_bf16(                \
            FAC[m], FBC[n], acc[m][n], 0, 0, 0);                            \
    __builtin_amdgcn_s_setprio(0);                                          \
    __builtin_amdgcn_s_barrier();                                           \
  }

  for (int s = 0; s < NT - 4; s += 4) {
    GITER(s + 0, 1, 3, 1, KEEPM, 1, fa0, fb0, fa1, fb1)
    GITER(s + 1, 2, 0, 1, KEEPM, 1, fa1, fb1, fa0, fb0)
    GITER(s + 2, 3, 1, 1, KEEPM, 1, fa0, fb0, fa1, fb1)
    GITER(s + 3, 0, 2, 1, KEEPM, 1, fa1, fb1, fa0, fb0)
  }
  GITER(NT - 4, 1, 3, 1, KEEPM, 1, fa0, fb0, fa1, fb1)
  GITER(NT - 3, 2, 0, 0, KEEP1, 1, fa1, fb1, fa0, fb0)
  GITER(NT - 2, 3, 1, 0, 0,     1, fa0, fb0, fa1, fb1)
  GITER(NT - 1, 0, 2, 0, 0,     0, fa1, fb1, fa0, fb0)
#undef GITER
#undef STAGE

  // ---- epilogue. C/D layout: col = lane&15, row = (lane>>4)*4 + j.
  const int crow0 = brow * BM + wr * WM;
  const int ccol0 = bcol * BN + wc * WN + (lane & 15);
  const int rsub  = (lane >> 4) * 4;

  if (MODE == 0) {
    unsigned short* H = (unsigned short*)Cout;
#pragma unroll
    for (int m = 0; m < MF; ++m) {
      const int rbase = crow0 + m * 16 + rsub;
      int   ia[4][4];
      float wa[4][4];
#pragma unroll
      for (int j = 0; j < 4; ++j) {
        const int4   iq = *(const int4*)(pidx + (size_t)(rbase + j) * 4);
        const float4 wq = *(const float4*)(pwt + (size_t)(rbase + j) * 4);
        ia[j][0] = iq.x; ia[j][1] = iq.y; ia[j][2] = iq.z; ia[j][3] = iq.w;
        wa[j][0] = wq.x; wa[j][1] = wq.y; wa[j][2] = wq.z; wa[j][3] = wq.w;
      }
#pragma unroll
      for (int n = 0; n < NF; ++n) {
        const int col = ccol0 + n * 16;
        const float ub = bias[col];
#pragma unroll
        for (int j = 0; j < 4; ++j) {
          float g = wa[j][0] * gates[(size_t)ia[j][0] * DFF + col]
                  + wa[j][1] * gates[(size_t)ia[j][1] * DFF + col]
                  + wa[j][2] * gates[(size_t)ia[j][2] * DFF + col]
                  + wa[j][3] * gates[(size_t)ia[j][3] * DFF + col];
          const float u   = acc[m][n][j] + ub;
          const float val = u * (1.f / (1.f + __expf(-g)));
          const float h   = 0.5f * val * (1.f + erff(val * 0.70710678118654752f));
          H[(size_t)(rbase + j) * N + col] = f2bf(h);
        }
      }
    }
  } else {
    float* O = (float*)Cout;
#pragma unroll
    for (int m = 0; m < MF; ++m) {
      const int rbase = crow0 + m * 16 + rsub;
#pragma unroll
      for (int n = 0; n < NF; ++n) {
        const int col = ccol0 + n * 16;
        const float db = bias[col];
#pragma unroll
        for (int j = 0; j < 4; ++j)
          O[(size_t)(rbase + j) * N + col] = acc[m][n][j] + db;
      }
    }
  }
}

// ---------------------------------------------------------------------- launch
extern "C" void kernel_launch(void* const* d_in, const int* in_sizes, int n_in,
                              void* d_out, int out_size, void* d_ws, size_t ws_size,
                              hipStream_t stream) {
  const float* x     = (const float*)d_in[0];
  const float* tw    = (const float*)d_in[3];
  const float* sn    = (const float*)d_in[4];
  const float* pq    = (const float*)d_in[5];
  const float* gates = (const float*)d_in[6];
  const float* upw   = (const float*)d_in[7];
  const float* upb   = (const float*)d_in[8];
  const float* dnw   = (const float*)d_in[9];
  const float* dnb   = (const float*)d_in[10];
  float* out = (float*)d_out;

  char* p = (char*)d_ws;
  unsigned short* xb  = (unsigned short*)p; p += (size_t)R_ * DM * 2;
  unsigned short* uwb = (unsigned short*)p; p += (size_t)DFF * DM * 2;
  unsigned short* dwb = (unsigned short*)p; p += (size_t)DM * DFF * 2;
  unsigned short* H   = (unsigned short*)p; p += (size_t)R_ * DFF * 2;
  int*   pidx = (int*)p;   p += (size_t)R_ * 4 * sizeof(int);
  float* pwt  = (float*)p; p += (size_t)R_ * 4 * sizeof(float);
  float* vbuf = (float*)p; p += (size_t)R_ * DM * sizeof(float);

  cvt_bf16_kernel<<<(R_ * DM / 8) / 256, 256, 0, stream>>>(x, xb, R_ * DM / 8);
  cvt_bf16_kernel<<<(DFF * DM / 8) / 256, 256, 0, stream>>>(upw, uwb, DFF * DM / 8);
  cvt_bf16_kernel<<<(DM * DFF / 8) / 256, 256, 0, stream>>>(dnw, dwb, DM * DFF / 8);

  vcomp_kernel<<<R_, 256, 0, stream>>>(sn, tw, vbuf);
  score_kernel<<<R_ / 16, 256, 0, stream>>>(vbuf, pq, pidx, pwt);

  // GEMM1: M=8192 N=4096 K=1024, tile 256x256, waves 2x4 (WM=128,WN=64),
  //        RING=4*32KB = 128KB LDS, grid 512.
  auto* k1 = gemm_kernel<DM, DFF, 256, 256, 128, 64, 0>;
  // GEMM2: M=8192 N=1024 K=4096, tile 256x128, waves 4x2 (WM=64,WN=64),
  //        RING=4*24KB = 96KB LDS, grid 256.
  auto* k2 = gemm_kernel<DFF, DM, 256, 128, 64, 64, 1>;
  hipFuncSetAttribute((const void*)k1, hipFuncAttributeMaxDynamicSharedMemorySize,
                      4 * (256 + 256) * 64);
  hipFuncSetAttribute((const void*)k2, hipFuncAttributeMaxDynamicSharedMemorySize,
                      4 * (256 + 128) * 64);

  k1<<<(R_ / 256) * (DFF / 256), 512, 4 * (256 + 256) * 64, stream>>>(
      xb, uwb, upb, pidx, pwt, gates, (void*)H);
  k2<<<(R_ / 256) * (DM / 128), 512, 4 * (256 + 128) * 64, stream>>>(
      H, dwb, dnb, nullptr, nullptr, nullptr, (void*)out);
}